// Round 6
// baseline (267.074 us; speedup 1.0000x reference)
//
#include <hip/hip_runtime.h>

// DeformConv fused pipeline, MI355X gfx950.
// Shapes (hard-coded per reference): B=2, Ci=Co=256, H=W=96.
// R6 changes vs R5 (dcn_gemm 148us latency-bound; chain LDS->addr->gather->bar):
//  - K axis permuted to k-major (kk' = k*256 + c), mirrored in cvt_w9: per
//    8-chunk group the kernel-tap k is FIXED -> off/wt held in registers.
//  - one raw s_barrier per chunk; counted vmcnt (6 consume / 4 pre-barrier);
//    gather depth-2, A-stage depth-1; final k-group peeled with exact counts.
//  - off_conv3: depth-4 rolling window on x loads.

typedef unsigned short ushort_t;
typedef unsigned int uint_t;
typedef __attribute__((ext_vector_type(8))) short bf16x8;
typedef __attribute__((ext_vector_type(4))) float f32x4;
typedef __attribute__((ext_vector_type(2), aligned(4))) float f32x2a;  // 4B-aligned float2

#define HH 96
#define WW 96
#define HWSZ 9216
#define CI 256
#define CO 256
#define NB 2
#define NPIX 18432           // NB*HWSZ
#define KTOT 2304            // CI*9
#define BM 256
#define BN 32
#define BK 32
#define NCHUNK 72            // KTOT/BK

__device__ __forceinline__ ushort_t f2bf(float f) {
  unsigned int u = __float_as_uint(f);
  u += 0x7fffu + ((u >> 16) & 1u);   // RNE
  return (ushort_t)(u >> 16);
}

__device__ __forceinline__ void gload16(const void* g, void* l) {
  __builtin_amdgcn_global_load_lds(
      (const __attribute__((address_space(1))) unsigned int*)g,
      (__attribute__((address_space(3))) unsigned int*)l, 16, 0, 0);
}

// ---------------- 1a) w_dcn -> bf16, K-permuted k-major, per-chunk [ko][kg][m][8] ----------------
// kk' = t*256 + ci ; chunk ko' = kk'>>5 ; dest = ko'*8192 + kg*2048 + oo*8 + j
__global__ void cvt_w9(const float* __restrict__ w, ushort_t* __restrict__ o) {
  int i = blockIdx.x * 256 + threadIdx.x;     // i = oo*KTOT + ci*9 + t, grid exact
  int oo = i / KTOT;
  int r = i - oo * KTOT;
  int ci = r / 9, t = r - ci * 9;
  int kkp = t * 256 + ci;
  int ko = kkp >> 5, kg = (kkp >> 3) & 3, j = kkp & 7;
  o[ko * 8192 + kg * 2048 + oo * 8 + j] = f2bf(w[i]);
}

// ---------------- 1b) w_off [ch][ci][t] -> [ci][ch*9+t] ----------------
__global__ void cvt_wofft(const float* __restrict__ w, float* __restrict__ o) {
  int i = blockIdx.x * 256 + threadIdx.x;     // exact: 27*2304 = 62208
  int ch = i / 2304;
  int r = i - ch * 2304;
  int ci = r / 9, t = r - ci * 9;
  o[ci * 243 + ch * 9 + t] = w[i];
}

// ---------------- 2) offset conv: wave-per-channel-group, depth-4 x window ----------------
// om_part layout: [2 part][27 ch][NPIX]. Block = 64 px x 4 waves; wave w owns
// channels [7w, 7w+7) (wave 3: 6). Weights wave-uniform -> scalar loads.
__global__ __launch_bounds__(256, 4) void off_conv3(
    const float* __restrict__ x, const float* __restrict__ w_offt,
    float* __restrict__ om_part) {
  const int tid = threadIdx.x;
  const int lane = tid & 63;
  const int wid = __builtin_amdgcn_readfirstlane(tid >> 6);
  const int n = blockIdx.x * 64 + lane;        // grid.x = NPIX/64 = 288
  const int part = blockIdx.y;                  // 0..1 -> 128 ci each
  const int b = n / HWSZ;
  const int hw = n - b * HWSZ;
  const int h = hw / WW, w = hw - h * WW;
  const float* xp = x + (size_t)b * CI * HWSZ + hw;

  int soff[9]; float msk[9];
#pragma unroll
  for (int t = 0; t < 9; ++t) {
    int dy = t / 3 - 1, dx = t % 3 - 1;
    bool ok = (h + dy >= 0) && (h + dy < HH) && (w + dx >= 0) && (w + dx < WW);
    soff[t] = ok ? dy * WW + dx : 0;
    msk[t] = ok ? 1.f : 0.f;
  }

  const int ch0 = wid * 7;
  const int nch = (wid < 3) ? 7 : 6;
  float acc[7];
#pragma unroll
  for (int i = 0; i < 7; ++i) acc[i] = 0.f;

  const int ci0 = part * 128;
  const float* wbase = w_offt + ch0 * 9;

  float win[4][9];
#pragma unroll
  for (int a = 0; a < 4; ++a) {
    const float* xc = xp + (size_t)(ci0 + a) * HWSZ;
#pragma unroll
    for (int t = 0; t < 9; ++t) win[a][t] = xc[soff[t]] * msk[t];
  }
  for (int ci = ci0; ci < ci0 + 128; ci += 4) {
#pragma unroll
    for (int a = 0; a < 4; ++a) {
      const float* wp = wbase + (ci + a) * 243;     // wave-uniform -> s_load
#pragma unroll
      for (int ch = 0; ch < 7; ++ch)                // wave3 ch6 reads pad, discarded
#pragma unroll
        for (int t = 0; t < 9; ++t)
          acc[ch] = fmaf(win[a][t], wp[ch * 9 + t], acc[ch]);
      int cin = ci + 4 + a;                         // refill 4 ahead (clamped)
      if (cin > ci0 + 127) cin = ci0 + 127;
      const float* xc = xp + (size_t)cin * HWSZ;
#pragma unroll
      for (int t = 0; t < 9; ++t) win[a][t] = xc[soff[t]] * msk[t];
    }
  }
#pragma unroll
  for (int ch = 0; ch < 7; ++ch)
    if (ch < nch)
      om_part[((size_t)(part * 27 + ch0 + ch)) * NPIX + n] = acc[ch];
}

// ---------------- 3) prep: coords -> row-pair offsets + folded weights (SoA [k][n]) ----------------
__global__ void prep_kernel(const float* __restrict__ om_part, const float* __restrict__ b_off,
                            uint_t* __restrict__ offs, float4* __restrict__ wts) {
  int n = blockIdx.x * 128 + threadIdx.x;       // grid 144 x 128
  float om[27];
#pragma unroll
  for (int ch = 0; ch < 27; ++ch) {
    float s = b_off[ch];
#pragma unroll
    for (int p = 0; p < 2; ++p)
      s += om_part[((size_t)p * 27 + ch) * NPIX + n];
    om[ch] = s;
  }
  int hw = n % HWSZ;
  int h = hw / WW;
  int w = hw - h * WW;
#pragma unroll
  for (int k = 0; k < 9; ++k) {
    float dy = om[2 * k];
    float dx = om[2 * k + 1];
    float mk = 1.f / (1.f + __expf(-om[18 + k]));
    float py = dy + (float)(h - 1 + k / 3);
    float px = dx + (float)(w - 1 + k % 3);
    float y0f = floorf(py), x0f = floorf(px);
    int y0 = (int)y0f, x0 = (int)x0f;
    float wy1 = py - y0f, wx1 = px - x0f;
    float wy0 = 1.f - wy1, wx0 = 1.f - wx1;
    float vy0 = (y0 >= 0 && y0 <= HH - 1) ? 1.f : 0.f;
    float vy1 = (y0 + 1 >= 0 && y0 + 1 <= HH - 1) ? 1.f : 0.f;
    int yc0 = min(max(y0, 0), HH - 1), yc1 = min(max(y0 + 1, 0), HH - 1);
    int xa = min(max(x0, 0), WW - 2);
    float a_, b_;
    if (x0 >= 0 && x0 <= WW - 2)      { a_ = wx0; b_ = wx1; }
    else if (x0 == -1)                { a_ = wx1; b_ = 0.f; }
    else if (x0 == WW - 1)            { a_ = 0.f; b_ = wx0; }
    else                              { a_ = 0.f; b_ = 0.f; }
    float s0 = mk * vy0 * wy0, s1 = mk * vy1 * wy1;
    offs[(size_t)k * NPIX + n] = (uint_t)(yc0 * WW + xa) | ((uint_t)(yc1 * WW + xa) << 16);
    wts[(size_t)k * NPIX + n] = make_float4(a_ * s0, b_ * s0, a_ * s1, b_ * s1);
  }
}

// ---------------- 4) fused sample + GEMM (k-major K order) ----------------
// Chunk j (0..71): tap k = j>>3 (fixed per 8 chunks), channels c = 32*(j&7)+idx.
// Thread sk2 (0..15) samples c-pair {32*(j&7)+2*sk2, +1} at pixel sp with
// register-held (off,wt). One s_barrier/chunk; vmcnt(6)/vmcnt(4) counted waits.
#define CHUNK(U, KBASE, DOA, DOG, GOFF)                                         \
  {                                                                             \
    asm volatile("s_waitcnt vmcnt(6)" ::: "memory");                            \
    __builtin_amdgcn_sched_barrier(0);                                          \
    {                                                                           \
      float v0_ = wvc.x * g0[(U) & 1].x + wvc.y * g0[(U) & 1].y +               \
                  wvc.z * g1[(U) & 1].x + wvc.w * g1[(U) & 1].y;                \
      float v1_ = wvc.x * h0[(U) & 1].x + wvc.y * h0[(U) & 1].y +               \
                  wvc.z * h1[(U) & 1].x + wvc.w * h1[(U) & 1].y;                \
      uint_t pk_ = (uint_t)f2bf(v0_) | ((uint_t)f2bf(v1_) << 16);               \
      *(uint_t*)&Slds[(U) & 1][((sk2 >> 2) * 32 + sp) * 8 + (sk2 & 3) * 2] = pk_; \
    }                                                                           \
    asm volatile("s_waitcnt vmcnt(4) lgkmcnt(0)" ::: "memory");                 \
    __builtin_amdgcn_s_barrier();                                               \
    __builtin_amdgcn_sched_barrier(0);                                          \
    if (DOA) {                                                                  \
      const ushort_t* ga_ = w9r + (size_t)((KBASE) + (U) + 1) * 8192 + tid * 8; \
      gload16(ga_, &Alds[((U) + 1) & 1][wid * 512]);                            \
      gload16(ga_ + 4096, &Alds[((U) + 1) & 1][4096 + wid * 512]);              \
    }                                                                           \
    {                                                                           \
      bf16x8 bfr_ = *(const bf16x8*)&Slds[(U) & 1][(lg * 32 + wc * 16 + lm) * 8]; \
      _Pragma("unroll")                                                         \
      for (int mi_ = 0; mi_ < 4; ++mi_) {                                       \
        bf16x8 af_ = *(const bf16x8*)&Alds[(U) & 1][(lg * 256 + wr * 64 + mi_ * 16 + lm) * 8]; \
        acc[mi_] = __builtin_amdgcn_mfma_f32_16x16x32_bf16(af_, bfr_, acc[mi_], 0, 0, 0); \
      }                                                                         \
    }                                                                           \
    if (DOG) {                                                                  \
      int ob_ = (32 * (((U) + 2) & 7) + sk2 * 2) * HWSZ;                        \
      g0[(U) & 1] = *(const f32x2a*)(xb + ob_ + (int)((GOFF) & 0xffffu));       \
      g1[(U) & 1] = *(const f32x2a*)(xb + ob_ + (int)((GOFF) >> 16));           \
      h0[(U) & 1] = *(const f32x2a*)(xb + ob_ + HWSZ + (int)((GOFF) & 0xffffu)); \
      h1[(U) & 1] = *(const f32x2a*)(xb + ob_ + HWSZ + (int)((GOFF) >> 16));    \
    }                                                                           \
  }

__global__ __launch_bounds__(512, 4) void dcn_gemm(
    const float* __restrict__ x, const ushort_t* __restrict__ w9r,
    const uint_t* __restrict__ offs, const float4* __restrict__ wts,
    const float* __restrict__ b_dcn, float* __restrict__ out) {
  __shared__ __align__(16) ushort_t Alds[2][8192];   // 32 KB
  __shared__ __align__(16) ushort_t Slds[2][1024];   // 4 KB
  __shared__ uint_t off_l[9][32];                    // 1.1 KB
  __shared__ __align__(16) float4 wt_l[9][32];       // 4.6 KB

  const int tid = threadIdx.x;
  const int p0 = blockIdx.x * BN;             // grid.x = 576
  const int bimg = p0 / HWSZ;                 // uniform per tile
  const int hw0 = p0 - bimg * HWSZ;
  const float* xb = x + (size_t)bimg * CI * HWSZ;

  for (int e = tid; e < 9 * BN; e += 512) {
    int k = e >> 5, p = e & 31;
    off_l[k][p] = offs[(size_t)k * NPIX + p0 + p];
    wt_l[k][p] = wts[(size_t)k * NPIX + p0 + p];
  }

  f32x4 acc[4];
#pragma unroll
  for (int i = 0; i < 4; ++i) acc[i] = (f32x4){0.f, 0.f, 0.f, 0.f};

  const int lane = tid & 63, wid = tid >> 6;
  const int wr = wid >> 1, wc = wid & 1;      // wave tile: rows wr*64, cols wc*16
  const int lg = lane >> 4, lm = lane & 15;
  const int sp = tid & 31;                    // pixel within tile
  const int sk2 = tid >> 5;                   // 0..15 -> c-pair index

  __syncthreads();  // prep tables visible

  uint_t oc = off_l[0][sp];
  float4 wvc = wt_l[0][sp];
  f32x2a g0[2], g1[2], h0[2], h1[2];

  // ---- prologue: G(0), A(0), G(1)  (order fixes vmcnt accounting) ----
  {
    int ob = (sk2 * 2) * HWSZ;
    g0[0] = *(const f32x2a*)(xb + ob + (int)(oc & 0xffffu));
    g1[0] = *(const f32x2a*)(xb + ob + (int)(oc >> 16));
    h0[0] = *(const f32x2a*)(xb + ob + HWSZ + (int)(oc & 0xffffu));
    h1[0] = *(const f32x2a*)(xb + ob + HWSZ + (int)(oc >> 16));
    const ushort_t* ga = w9r + tid * 8;
    gload16(ga, &Alds[0][wid * 512]);
    gload16(ga + 4096, &Alds[0][4096 + wid * 512]);
    int ob1 = (32 + sk2 * 2) * HWSZ;
    g0[1] = *(const f32x2a*)(xb + ob1 + (int)(oc & 0xffffu));
    g1[1] = *(const f32x2a*)(xb + ob1 + (int)(oc >> 16));
    h0[1] = *(const f32x2a*)(xb + ob1 + HWSZ + (int)(oc & 0xffffu));
    h1[1] = *(const f32x2a*)(xb + ob1 + HWSZ + (int)(oc >> 16));
  }

  for (int k = 0; k < 8; ++k) {               // groups 0..7 (chunks 0..63)
    uint_t on = off_l[k + 1][sp];
    float4 wvn = wt_l[k + 1][sp];
    const int kb = k * 8;
    CHUNK(0, kb, true, true, oc)
    CHUNK(1, kb, true, true, oc)
    CHUNK(2, kb, true, true, oc)
    CHUNK(3, kb, true, true, oc)
    CHUNK(4, kb, true, true, oc)
    CHUNK(5, kb, true, true, oc)
    CHUNK(6, kb, true, true, on)
    CHUNK(7, kb, true, true, on)
    oc = on; wvc = wvn;
  }
  // ---- peeled group 8 (chunks 64..71) ----
  CHUNK(0, 64, true, true, oc)
  CHUNK(1, 64, true, true, oc)
  CHUNK(2, 64, true, true, oc)
  CHUNK(3, 64, true, true, oc)
  CHUNK(4, 64, true, true, oc)
  CHUNK(5, 64, true, true, oc)
  CHUNK(6, 64, true, false, oc)
  {  // chunk 71: exact drain counts
    asm volatile("s_waitcnt vmcnt(2)" ::: "memory");
    __builtin_amdgcn_sched_barrier(0);
    {
      float v0_ = wvc.x * g0[1].x + wvc.y * g0[1].y + wvc.z * g1[1].x + wvc.w * g1[1].y;
      float v1_ = wvc.x * h0[1].x + wvc.y * h0[1].y + wvc.z * h1[1].x + wvc.w * h1[1].y;
      uint_t pk_ = (uint_t)f2bf(v0_) | ((uint_t)f2bf(v1_) << 16);
      *(uint_t*)&Slds[1][((sk2 >> 2) * 32 + sp) * 8 + (sk2 & 3) * 2] = pk_;
    }
    asm volatile("s_waitcnt vmcnt(0) lgkmcnt(0)" ::: "memory");
    __builtin_amdgcn_s_barrier();
    __builtin_amdgcn_sched_barrier(0);
    {
      bf16x8 bfr_ = *(const bf16x8*)&Slds[1][(lg * 32 + wc * 16 + lm) * 8];
#pragma unroll
      for (int mi_ = 0; mi_ < 4; ++mi_) {
        bf16x8 af_ = *(const bf16x8*)&Alds[1][(lg * 256 + wr * 64 + mi_ * 16 + lm) * 8];
        acc[mi_] = __builtin_amdgcn_mfma_f32_16x16x32_bf16(af_, bfr_, acc[mi_], 0, 0, 0);
      }
    }
  }

  // ---- epilogue: + b_dcn, store pre-BN fp32 ----
  const int hwv = hw0 + wc * 16 + lm;
#pragma unroll
  for (int mi = 0; mi < 4; ++mi) {
    int obase = wr * 64 + mi * 16 + lg * 4;
#pragma unroll
    for (int r = 0; r < 4; ++r) {
      int o = obase + r;
      out[((size_t)(bimg * CO + o)) * HWSZ + hwv] = acc[mi][r] + b_dcn[o];
    }
  }
}

// ---------------- 5) BN stats ----------------
__global__ void bn_stats(const float* __restrict__ out, const float* __restrict__ gamma,
                         const float* __restrict__ beta, float* __restrict__ ss) {
  int o = blockIdx.x;
  int tid = threadIdx.x;
  float s = 0.f, sq = 0.f;
#pragma unroll
  for (int b = 0; b < NB; ++b) {
    const float4* p = (const float4*)(out + ((size_t)(b * CO + o)) * HWSZ);
    for (int j = tid; j < HWSZ / 4; j += 256) {
      float4 v = p[j];
      s += v.x + v.y + v.z + v.w;
      sq += v.x * v.x + v.y * v.y + v.z * v.z + v.w * v.w;
    }
  }
#pragma unroll
  for (int off = 32; off > 0; off >>= 1) {
    s += __shfl_xor(s, off);
    sq += __shfl_xor(sq, off);
  }
  __shared__ float rs[4], rq[4];
  if ((tid & 63) == 0) { rs[tid >> 6] = s; rq[tid >> 6] = sq; }
  __syncthreads();
  if (tid == 0) {
    s = rs[0] + rs[1] + rs[2] + rs[3];
    sq = rq[0] + rq[1] + rq[2] + rq[3];
    float mean = s * (1.f / (float)NPIX);
    float var = sq * (1.f / (float)NPIX) - mean * mean;
    float rstd = rsqrtf(var + 1e-5f);
    float sc = rstd * gamma[o];
    ss[o] = sc;
    ss[CO + o] = beta[o] - mean * sc;
  }
}

// ---------------- 6) BN apply + ReLU ----------------
__global__ void bn_apply(float* __restrict__ out, const float* __restrict__ ss) {
  int i = blockIdx.x * 256 + threadIdx.x;  // float4 index, exact grid
  float4 v = ((float4*)out)[i];
  int o = (i / (HWSZ / 4)) & 255;
  float sc = ss[o], sh = ss[CO + o];
  v.x = fmaxf(v.x * sc + sh, 0.f);
  v.y = fmaxf(v.y * sc + sh, 0.f);
  v.z = fmaxf(v.z * sc + sh, 0.f);
  v.w = fmaxf(v.w * sc + sh, 0.f);
  ((float4*)out)[i] = v;
}

extern "C" void kernel_launch(void* const* d_in, const int* in_sizes, int n_in,
                              void* d_out, int out_size, void* d_ws, size_t ws_size,
                              hipStream_t stream) {
  const float* x = (const float*)d_in[0];
  const float* w_off = (const float*)d_in[1];
  const float* b_off = (const float*)d_in[2];
  const float* w_dcn = (const float*)d_in[3];
  const float* b_dcn = (const float*)d_in[4];
  const float* gamma = (const float*)d_in[5];
  const float* beta = (const float*)d_in[6];
  float* out = (float*)d_out;

  // ws layout (bytes): total ~8.73 MB
  char* ws = (char*)d_ws;
  float* om_part = (float*)(ws);                         // 2*27*18432*4 = 3,981,312 B
  uint_t* offs = (uint_t*)(ws + 3981312);                // 9*18432*4  =   663,552 B
  float4* wts = (float4*)(ws + 4644864);                 // 9*18432*16 = 2,654,208 B
  ushort_t* w9r = (ushort_t*)(ws + 7299072);             // 2304*256*2 = 1,179,648 B
  float* w_offt = (float*)(ws + 8478720);                // 256*243*4 + pad
  float* ss = (float*)(ws + 8728576);                    // 512 f

  cvt_w9<<<(CO * KTOT) / 256, 256, 0, stream>>>(w_dcn, w9r);
  cvt_wofft<<<(27 * KTOT) / 256, 256, 0, stream>>>(w_off, w_offt);
  off_conv3<<<dim3(NPIX / 64, 2), 256, 0, stream>>>(x, w_offt, om_part);
  prep_kernel<<<NPIX / 128, 128, 0, stream>>>(om_part, b_off, offs, wts);
  dcn_gemm<<<NPIX / BN, 512, 0, stream>>>(x, w9r, offs, wts, b_dcn, out);
  bn_stats<<<CO, 256, 0, stream>>>(out, gamma, beta, ss);
  bn_apply<<<(out_size / 4) / 256, 256, 0, stream>>>(out, ss);
}

// Round 7
// 261.437 us; speedup vs baseline: 1.0216x; 1.0216x over previous
//
#include <hip/hip_runtime.h>

// DeformConv fused pipeline, MI355X gfx950. Shapes: B=2, Ci=Co=256, H=W=96.
// R7: decouple. (a) off_gemm: om = W27 x im2col(x) via MFMA (replaces 80us
// VALU off_conv). (b) sample_s: materialize S[2304][18432] bf16 (85 MB ws)
// c-major (9-tap L1 reuse), coalesced 16B stores via static j-phase packing.
// (c) s_gemm: plain bf16 MFMA GEMM streaming S with counted vmcnt.
// Fallback (ws < 92MB): R5's fused dcn_gemm (148us known-good).

typedef unsigned short ushort_t;
typedef unsigned int uint_t;
typedef __attribute__((ext_vector_type(8))) short bf16x8;
typedef __attribute__((ext_vector_type(4))) float f32x4;
typedef __attribute__((ext_vector_type(2), aligned(4))) float f32x2a;

#define HH 96
#define WW 96
#define HWSZ 9216
#define CI 256
#define CO 256
#define NB 2
#define NPIX 18432
#define KTOT 2304

__device__ __forceinline__ ushort_t f2bf(float f) {
  unsigned int u = __float_as_uint(f);
  u += 0x7fffu + ((u >> 16) & 1u);
  return (ushort_t)(u >> 16);
}
__device__ __forceinline__ float u2f(uint_t u) { return __uint_as_float(u); }

__device__ __forceinline__ void gload16(const void* g, void* l) {
  __builtin_amdgcn_global_load_lds(
      (const __attribute__((address_space(1))) unsigned int*)g,
      (__attribute__((address_space(3))) unsigned int*)l, 16, 0, 0);
}

// ---------------- cvt_w9: w_dcn -> bf16 [kk>>3][m][kk&7] ----------------
__global__ void cvt_w9(const float* __restrict__ w, ushort_t* __restrict__ o) {
  int i = blockIdx.x * 256 + threadIdx.x;      // grid exact CO*KTOT
  int oo = i / KTOT;
  int kk = i - oo * KTOT;
  o[(kk >> 3) * 2048 + oo * 8 + (kk & 7)] = f2bf(w[i]);
}

// ---------------- cvt_woff9: w_off -> bf16 [kk>>3][m32][kk&7], rows>=27 zero ----
__global__ void cvt_woff9(const float* __restrict__ w, ushort_t* __restrict__ o) {
  int i = blockIdx.x * 256 + threadIdx.x;      // grid exact 32*KTOT
  int m = i / KTOT;
  int kk = i - m * KTOT;
  float v = (m < 27) ? w[m * KTOT + kk] : 0.f;
  o[(kk >> 3) * 256 + m * 8 + (kk & 7)] = f2bf(v);
}

// ---------------- off_gemm: om[27][NPIX] = W27 * im2col(x) ----------------
// BM=32(27), BN=64, BK=64, 36 chunks, 512 thr / 8 waves, wave-tile 16x16.
__global__ __launch_bounds__(512, 2) void off_gemm(
    const float* __restrict__ x, const ushort_t* __restrict__ w27r,
    float* __restrict__ om) {
  __shared__ __align__(16) ushort_t A27[2][2048];
  __shared__ __align__(16) ushort_t B64[2][4096];
  __shared__ uint2 tbl[9][64];                 // {abs idx (0 if invalid), mask}

  const int tid = threadIdx.x;
  const int lane = tid & 63, wid = tid >> 6;
  const int p0 = blockIdx.x * 64;
  const int bimg = p0 / HWSZ;
  const int hw0 = p0 - bimg * HWSZ;
  const float* xb = x + (size_t)bimg * CI * HWSZ;

  for (int e = tid; e < 576; e += 512) {
    int k = e >> 6, px = e & 63;
    int hw = hw0 + px, h = hw / WW, w_ = hw - h * WW;
    int dy = k / 3 - 1, dx = k % 3 - 1;
    bool ok = (h + dy >= 0) && (h + dy < HH) && (w_ + dx >= 0) && (w_ + dx < WW);
    tbl[k][px] = make_uint2(ok ? (uint_t)(hw + dy * WW + dx) : 0u,
                            ok ? 0x3f800000u : 0u);
  }

  const int lg = lane >> 4, lm = lane & 15;
  const int wr = wid >> 2, wc = wid & 3;
  f32x4 acc = (f32x4){0.f, 0.f, 0.f, 0.f};

  int cj[8], kj[8];
#pragma unroll
  for (int j = 0; j < 8; ++j) {
    int kk = wid * 8 + j;                      // chunk 0
    cj[j] = kk / 9;
    kj[j] = kk - 9 * cj[j];
  }
  __syncthreads();

#define OG_STAGE(CH, BUF)                                                     \
  {                                                                           \
    float raw[8], mkk[8];                                                     \
    _Pragma("unroll") for (int j = 0; j < 8; ++j) {                           \
      uint2 e_ = tbl[kj[j]][lane];                                            \
      raw[j] = xb[cj[j] * HWSZ + (int)e_.x];                                  \
      mkk[j] = u2f(e_.y);                                                     \
      kj[j] += 1; cj[j] += 7;                                                 \
      if (kj[j] == 9) { kj[j] = 0; cj[j] += 1; }                              \
    }                                                                         \
    gload16(w27r + (size_t)(CH) * 2048 + (tid & 255) * 8,                     \
            &A27[BUF][(wid & 3) * 512]);                                      \
    ushort_t sv_[8] __attribute__((aligned(16)));                             \
    _Pragma("unroll") for (int j = 0; j < 8; ++j) sv_[j] = f2bf(raw[j] * mkk[j]); \
    *(uint4*)&B64[BUF][tid * 8] = *(const uint4*)sv_;                         \
  }

  OG_STAGE(0, 0)                                // prologue: chunk 0
  for (int ko = 0; ko < 36; ++ko) {
    const int cur = ko & 1, nxt = cur ^ 1;
    if (ko < 35) OG_STAGE(ko + 1, nxt)
    asm volatile("s_waitcnt vmcnt(0) lgkmcnt(0)" ::: "memory");
    __builtin_amdgcn_s_barrier();
    __builtin_amdgcn_sched_barrier(0);
#pragma unroll
    for (int s = 0; s < 2; ++s) {
      bf16x8 af = *(const bf16x8*)&A27[cur][((s * 4 + lg) * 32 + wr * 16 + lm) * 8];
      bf16x8 bfv = *(const bf16x8*)&B64[cur][((s * 4 + lg) * 64 + wc * 16 + lm) * 8];
      acc = __builtin_amdgcn_mfma_f32_16x16x32_bf16(af, bfv, acc, 0, 0, 0);
    }
    asm volatile("s_waitcnt lgkmcnt(0)" ::: "memory");
    __builtin_amdgcn_s_barrier();
    __builtin_amdgcn_sched_barrier(0);
  }
#undef OG_STAGE

  int row = wr * 16 + lg * 4;
  int col = p0 + wc * 16 + lm;
#pragma unroll
  for (int r = 0; r < 4; ++r)
    if (row + r < 27) om[(size_t)(row + r) * NPIX + col] = acc[r];
}

// ---------------- prep1: om -> row-pair offsets + folded weights ----------------
__global__ void prep_kernel(const float* __restrict__ om, const float* __restrict__ b_off,
                            uint_t* __restrict__ offs, float4* __restrict__ wts) {
  int n = blockIdx.x * 128 + threadIdx.x;      // grid 144 x 128
  float omv[27];
#pragma unroll
  for (int ch = 0; ch < 27; ++ch) omv[ch] = b_off[ch] + om[(size_t)ch * NPIX + n];
  int hw = n % HWSZ;
  int h = hw / WW, w = hw - h * WW;
#pragma unroll
  for (int k = 0; k < 9; ++k) {
    float dy = omv[2 * k], dx = omv[2 * k + 1];
    float mk = 1.f / (1.f + __expf(-omv[18 + k]));
    float py = dy + (float)(h - 1 + k / 3);
    float px = dx + (float)(w - 1 + k % 3);
    float y0f = floorf(py), x0f = floorf(px);
    int y0 = (int)y0f, x0 = (int)x0f;
    float wy1 = py - y0f, wx1 = px - x0f;
    float wy0 = 1.f - wy1, wx0 = 1.f - wx1;
    float vy0 = (y0 >= 0 && y0 <= HH - 1) ? 1.f : 0.f;
    float vy1 = (y0 + 1 >= 0 && y0 + 1 <= HH - 1) ? 1.f : 0.f;
    int yc0 = min(max(y0, 0), HH - 1), yc1 = min(max(y0 + 1, 0), HH - 1);
    int xa = min(max(x0, 0), WW - 2);
    float a_, b_;
    if (x0 >= 0 && x0 <= WW - 2)      { a_ = wx0; b_ = wx1; }
    else if (x0 == -1)                { a_ = wx1; b_ = 0.f; }
    else if (x0 == WW - 1)            { a_ = 0.f; b_ = wx0; }
    else                              { a_ = 0.f; b_ = 0.f; }
    float s0 = mk * vy0 * wy0, s1 = mk * vy1 * wy1;
    offs[(size_t)k * NPIX + n] = (uint_t)(yc0 * WW + xa) | ((uint_t)(yc1 * WW + xa) << 16);
    wts[(size_t)k * NPIX + n] = make_float4(a_ * s0, b_ * s0, a_ * s1, b_ * s1);
  }
}

// ---------------- sample_s: S_g[kk>>3][n][kk&7] bf16 ----------------
// Block = 64 px, 8 waves; wave owns 32 consecutive c (9-tap L1 reuse).
// 8-c macro-iter: 72 kk = 9 aligned groups; group g completes at cl=g (g8 at 7).
__global__ __launch_bounds__(512, 2) void sample_s(
    const float* __restrict__ x, const uint_t* __restrict__ offs,
    const float4* __restrict__ wts, ushort_t* __restrict__ S_g) {
  const int tid = threadIdx.x;
  const int lane = tid & 63, wid = tid >> 6;
  const int p0 = blockIdx.x * 64;
  const int n = p0 + lane;
  const int bimg = p0 / HWSZ;
  const float* xb = x + (size_t)bimg * CI * HWSZ;

  uint_t ofr[9]; float4 wtr[9];
#pragma unroll
  for (int k = 0; k < 9; ++k) {
    ofr[k] = offs[(size_t)k * NPIX + n];
    wtr[k] = wts[(size_t)k * NPIX + n];
  }

  for (int ii = 0; ii < 4; ++ii) {
    const int c8 = wid * 32 + ii * 8;
    const size_t G0 = (size_t)9 * (wid * 4 + ii);
    ushort_t pk[9][8];
#pragma unroll
    for (int cl = 0; cl < 8; ++cl) {
      const float* xc = xb + (size_t)(c8 + cl) * HWSZ;
#pragma unroll
      for (int k = 0; k < 9; ++k) {
        const int q = 9 * cl + k;              // static
        uint_t o2 = ofr[k];
        float4 wv = wtr[k];
        f32x2a a = *(const f32x2a*)(xc + (o2 & 0xffffu));
        f32x2a b = *(const f32x2a*)(xc + (o2 >> 16));
        pk[q >> 3][q & 7] = f2bf(wv.x * a.x + wv.y * a.y + wv.z * b.x + wv.w * b.y);
      }
      *(uint4*)&S_g[((G0 + cl) * NPIX + n) * 8] = *(const uint4*)pk[cl];
      if (cl == 7)
        *(uint4*)&S_g[((G0 + 8) * NPIX + n) * 8] = *(const uint4*)pk[8];
    }
  }
}

// ---------------- s_gemm: out = W9 * S + b_dcn ----------------
// BM=256, BN=64, BK=64, 36 chunks, grid 288, 512 thr / 8 waves, wave 64x32.
__global__ __launch_bounds__(512, 2) void s_gemm(
    const ushort_t* __restrict__ w9r, const ushort_t* __restrict__ S_g,
    const float* __restrict__ b_dcn, float* __restrict__ out) {
  __shared__ __align__(16) ushort_t A[2][16384];   // 64 KB
  __shared__ __align__(16) ushort_t S[2][4096];    // 16 KB

  const int tid = threadIdx.x;
  const int lane = tid & 63, wid = tid >> 6;
  const int p0 = blockIdx.x * 64;
  const int bimg = p0 / HWSZ;
  const int hw0 = p0 - bimg * HWSZ;
  const int lg = lane >> 4, lm = lane & 15;
  const int wr = wid >> 1, wc = wid & 1;

  f32x4 acc[4][2];
#pragma unroll
  for (int i = 0; i < 4; ++i)
#pragma unroll
    for (int j = 0; j < 2; ++j) acc[i][j] = (f32x4){0.f, 0.f, 0.f, 0.f};

#define SG_STAGE(CH, BUF)                                                     \
  {                                                                           \
    _Pragma("unroll") for (int i = 0; i < 4; ++i)                             \
      gload16(w9r + (size_t)(CH) * 16384 + i * 4096 + tid * 8,                \
              &A[BUF][i * 4096 + wid * 512]);                                 \
    gload16(S_g + ((size_t)((CH) * 8 + wid) * NPIX + p0 + lane) * 8,          \
            &S[BUF][wid * 512]);                                              \
  }
#define SG_MFMA(BUF)                                                          \
  {                                                                           \
    _Pragma("unroll") for (int s = 0; s < 2; ++s) {                           \
      bf16x8 bfr0 = *(const bf16x8*)&S[BUF][((s * 4 + lg) * 64 + wc * 32 + lm) * 8];      \
      bf16x8 bfr1 = *(const bf16x8*)&S[BUF][((s * 4 + lg) * 64 + wc * 32 + 16 + lm) * 8]; \
      _Pragma("unroll") for (int mi = 0; mi < 4; ++mi) {                      \
        bf16x8 af = *(const bf16x8*)&A[BUF][((s * 4 + lg) * 256 + wr * 64 + mi * 16 + lm) * 8]; \
        acc[mi][0] = __builtin_amdgcn_mfma_f32_16x16x32_bf16(af, bfr0, acc[mi][0], 0, 0, 0); \
        acc[mi][1] = __builtin_amdgcn_mfma_f32_16x16x32_bf16(af, bfr1, acc[mi][1], 0, 0, 0); \
      }                                                                       \
    }                                                                         \
  }

  SG_STAGE(0, 0)
  for (int ko = 0; ko < 35; ++ko) {
    const int cur = ko & 1, nxt = cur ^ 1;
    SG_STAGE(ko + 1, nxt)
    asm volatile("s_waitcnt vmcnt(5) lgkmcnt(0)" ::: "memory");
    __builtin_amdgcn_s_barrier();
    __builtin_amdgcn_sched_barrier(0);
    SG_MFMA(cur)
    asm volatile("s_waitcnt lgkmcnt(0)" ::: "memory");
    __builtin_amdgcn_s_barrier();
    __builtin_amdgcn_sched_barrier(0);
  }
  asm volatile("s_waitcnt vmcnt(0) lgkmcnt(0)" ::: "memory");
  __builtin_amdgcn_s_barrier();
  __builtin_amdgcn_sched_barrier(0);
  SG_MFMA(1)
#undef SG_STAGE
#undef SG_MFMA

  const int hwv0 = hw0 + wc * 32 + lm;
#pragma unroll
  for (int mi = 0; mi < 4; ++mi) {
    int obase = wr * 64 + mi * 16 + lg * 4;
#pragma unroll
    for (int ni = 0; ni < 2; ++ni)
#pragma unroll
      for (int r = 0; r < 4; ++r) {
        int o = obase + r;
        out[((size_t)(bimg * CO + o)) * HWSZ + hwv0 + ni * 16] = acc[mi][ni][r] + b_dcn[o];
      }
  }
}

// ---------------- fallback: R5 fused sample+GEMM (small ws) ----------------
__global__ __launch_bounds__(512, 4) void dcn_gemm(
    const float* __restrict__ x, const ushort_t* __restrict__ w9r,
    const uint_t* __restrict__ offs, const float4* __restrict__ wts,
    const float* __restrict__ b_dcn, float* __restrict__ out) {
  __shared__ __align__(16) ushort_t Alds[2][8192];
  __shared__ __align__(16) ushort_t Slds[1024];
  __shared__ uint_t off_l[9][32];
  __shared__ __align__(16) float4 wt_l[9][32];

  const int tid = threadIdx.x;
  const int p0 = blockIdx.x * 32;
  const int bimg = p0 / HWSZ;
  const int hw0 = p0 - bimg * HWSZ;
  const float* xb = x + (size_t)bimg * CI * HWSZ;

  for (int e = tid; e < 9 * 32; e += 512) {
    int k = e >> 5, p = e & 31;
    off_l[k][p] = offs[(size_t)k * NPIX + p0 + p];
    wt_l[k][p] = wts[(size_t)k * NPIX + p0 + p];
  }
  f32x4 acc[4];
#pragma unroll
  for (int i = 0; i < 4; ++i) acc[i] = (f32x4){0.f, 0.f, 0.f, 0.f};

  const int lane = tid & 63, wid = tid >> 6;
  const int wr = wid >> 1, wc = wid & 1;
  const int lg = lane >> 4, lm = lane & 15;
  const int sp = tid & 31;
  const int sk2 = tid >> 5;
  int cb, kb;
  { int kkb = sk2 * 2; cb = kkb / 9; kb = kkb - cb * 9; }

  __syncthreads();

  f32x2a r0[2], r1[2];
  {
    int c = cb, k = kb;
#pragma unroll
    for (int j = 0; j < 2; ++j) {
      uint_t o2 = off_l[k][sp];
      const float* xc = xb + c * HWSZ;
      r0[j] = *(const f32x2a*)(xc + (o2 & 0xffffu));
      r1[j] = *(const f32x2a*)(xc + (o2 >> 16));
      ++k; if (k == 9) { k = 0; ++c; }
    }
    const ushort_t* ga = w9r + tid * 8;
    gload16(ga, &Alds[0][wid * 512]);
    gload16(ga + 4096, &Alds[0][4096 + wid * 512]);
  }

  for (int ko = 0; ko < 71; ++ko) {
    const int cur = ko & 1, nxt = cur ^ 1;
    {
      float v[2];
      int k = kb;
#pragma unroll
      for (int j = 0; j < 2; ++j) {
        float4 wv = wt_l[k][sp];
        v[j] = wv.x * r0[j].x + wv.y * r0[j].y + wv.z * r1[j].x + wv.w * r1[j].y;
        ++k; if (k == 9) k = 0;
      }
      uint_t pk = (uint_t)f2bf(v[0]) | ((uint_t)f2bf(v[1]) << 16);
      *(uint_t*)&Slds[((sk2 >> 2) * 32 + sp) * 8 + (sk2 & 3) * 2] = pk;
    }
    {
      kb += 5; cb += 3;
      if (kb >= 9) { kb -= 9; ++cb; }
      int c = cb, k = kb;
#pragma unroll
      for (int j = 0; j < 2; ++j) {
        uint_t o2 = off_l[k][sp];
        const float* xc = xb + c * HWSZ;
        r0[j] = *(const f32x2a*)(xc + (o2 & 0xffffu));
        r1[j] = *(const f32x2a*)(xc + (o2 >> 16));
        ++k; if (k == 9) { k = 0; ++c; }
      }
      const ushort_t* ga = w9r + (size_t)(ko + 1) * 8192 + tid * 8;
      gload16(ga, &Alds[nxt][wid * 512]);
      gload16(ga + 4096, &Alds[nxt][4096 + wid * 512]);
    }
    asm volatile("s_waitcnt vmcnt(6) lgkmcnt(0)" ::: "memory");
    __builtin_amdgcn_s_barrier();
    __builtin_amdgcn_sched_barrier(0);
    {
      bf16x8 bfr = *(const bf16x8*)&Slds[(lg * 32 + wc * 16 + lm) * 8];
#pragma unroll
      for (int mi = 0; mi < 4; ++mi) {
        bf16x8 af = *(const bf16x8*)&Alds[cur][(lg * 256 + wr * 64 + mi * 16 + lm) * 8];
        acc[mi] = __builtin_amdgcn_mfma_f32_16x16x32_bf16(af, bfr, acc[mi], 0, 0, 0);
      }
    }
    asm volatile("s_waitcnt lgkmcnt(0)" ::: "memory");
    __builtin_amdgcn_s_barrier();
    __builtin_amdgcn_sched_barrier(0);
  }
  {
    {
      float v[2];
      int k = kb;
#pragma unroll
      for (int j = 0; j < 2; ++j) {
        float4 wv = wt_l[k][sp];
        v[j] = wv.x * r0[j].x + wv.y * r0[j].y + wv.z * r1[j].x + wv.w * r1[j].y;
        ++k; if (k == 9) k = 0;
      }
      uint_t pk = (uint_t)f2bf(v[0]) | ((uint_t)f2bf(v[1]) << 16);
      *(uint_t*)&Slds[((sk2 >> 2) * 32 + sp) * 8 + (sk2 & 3) * 2] = pk;
    }
    asm volatile("s_waitcnt vmcnt(0) lgkmcnt(0)" ::: "memory");
    __builtin_amdgcn_s_barrier();
    __builtin_amdgcn_sched_barrier(0);
    bf16x8 bfr = *(const bf16x8*)&Slds[(lg * 32 + wc * 16 + lm) * 8];
#pragma unroll
    for (int mi = 0; mi < 4; ++mi) {
      bf16x8 af = *(const bf16x8*)&Alds[1][(lg * 256 + wr * 64 + mi * 16 + lm) * 8];
      acc[mi] = __builtin_amdgcn_mfma_f32_16x16x32_bf16(af, bfr, acc[mi], 0, 0, 0);
    }
  }
  const int hwv = hw0 + wc * 16 + lm;
#pragma unroll
  for (int mi = 0; mi < 4; ++mi) {
    int obase = wr * 64 + mi * 16 + lg * 4;
#pragma unroll
    for (int r = 0; r < 4; ++r) {
      int o = obase + r;
      out[((size_t)(bimg * CO + o)) * HWSZ + hwv] = acc[mi][r] + b_dcn[o];
    }
  }
}

// ---------------- BN stats ----------------
__global__ void bn_stats(const float* __restrict__ out, const float* __restrict__ gamma,
                         const float* __restrict__ beta, float* __restrict__ ss) {
  int o = blockIdx.x;
  int tid = threadIdx.x;
  float s = 0.f, sq = 0.f;
#pragma unroll
  for (int b = 0; b < NB; ++b) {
    const float4* p = (const float4*)(out + ((size_t)(b * CO + o)) * HWSZ);
    for (int j = tid; j < HWSZ / 4; j += 256) {
      float4 v = p[j];
      s += v.x + v.y + v.z + v.w;
      sq += v.x * v.x + v.y * v.y + v.z * v.z + v.w * v.w;
    }
  }
#pragma unroll
  for (int off = 32; off > 0; off >>= 1) {
    s += __shfl_xor(s, off);
    sq += __shfl_xor(sq, off);
  }
  __shared__ float rs[4], rq[4];
  if ((tid & 63) == 0) { rs[tid >> 6] = s; rq[tid >> 6] = sq; }
  __syncthreads();
  if (tid == 0) {
    s = rs[0] + rs[1] + rs[2] + rs[3];
    sq = rq[0] + rq[1] + rq[2] + rq[3];
    float mean = s * (1.f / (float)NPIX);
    float var = sq * (1.f / (float)NPIX) - mean * mean;
    float rstd = rsqrtf(var + 1e-5f);
    float sc = rstd * gamma[o];
    ss[o] = sc;
    ss[CO + o] = beta[o] - mean * sc;
  }
}

// ---------------- BN apply + ReLU ----------------
__global__ void bn_apply(float* __restrict__ out, const float* __restrict__ ss) {
  int i = blockIdx.x * 256 + threadIdx.x;
  float4 v = ((float4*)out)[i];
  int o = (i / (HWSZ / 4)) & 255;
  float sc = ss[o], sh = ss[CO + o];
  v.x = fmaxf(v.x * sc + sh, 0.f);
  v.y = fmaxf(v.y * sc + sh, 0.f);
  v.z = fmaxf(v.z * sc + sh, 0.f);
  v.w = fmaxf(v.w * sc + sh, 0.f);
  ((float4*)out)[i] = v;
}

extern "C" void kernel_launch(void* const* d_in, const int* in_sizes, int n_in,
                              void* d_out, int out_size, void* d_ws, size_t ws_size,
                              hipStream_t stream) {
  const float* x = (const float*)d_in[0];
  const float* w_off = (const float*)d_in[1];
  const float* b_off = (const float*)d_in[2];
  const float* w_dcn = (const float*)d_in[3];
  const float* b_dcn = (const float*)d_in[4];
  const float* gamma = (const float*)d_in[5];
  const float* beta = (const float*)d_in[6];
  float* out = (float*)d_out;

  char* ws = (char*)d_ws;
  const bool big = (ws_size >= (size_t)92 * 1024 * 1024);

  // common small buffers at tail region
  size_t base = big ? 84934656 : 0;            // S_g occupies [0, 84934656) if big
  ushort_t* S_g   = (ushort_t*)(ws);
  float*    om    = (float*)(ws + base);                    // 27*18432*4 = 1,990,656
  uint_t*   offs  = (uint_t*)(ws + base + 1990656);         //   663,552
  float4*   wts   = (float4*)(ws + base + 2654208);         // 2,654,208
  ushort_t* w9r   = (ushort_t*)(ws + base + 5308416);       // 1,179,648
  ushort_t* w27r  = (ushort_t*)(ws + base + 6488064);       //   147,456
  float*    ss    = (float*)(ws + base + 6635520);          //     2,048

  cvt_w9<<<(CO * KTOT) / 256, 256, 0, stream>>>(w_dcn, w9r);
  cvt_woff9<<<(32 * KTOT) / 256, 256, 0, stream>>>(w_off, w27r);
  off_gemm<<<NPIX / 64, 512, 0, stream>>>(x, w27r, om);
  prep_kernel<<<NPIX / 128, 128, 0, stream>>>(om, b_off, offs, wts);
  if (big) {
    sample_s<<<NPIX / 64, 512, 0, stream>>>(x, offs, wts, S_g);
    s_gemm<<<NPIX / 64, 512, 0, stream>>>(w9r, S_g, b_dcn, out);
  } else {
    dcn_gemm<<<NPIX / 32, 512, 0, stream>>>(x, w9r, offs, wts, b_dcn, out);
  }
  bn_stats<<<CO, 256, 0, stream>>>(out, gamma, beta, ss);
  bn_apply<<<(out_size / 4) / 256, 256, 0, stream>>>(out, ss);
}

// Round 8
// 219.550 us; speedup vs baseline: 1.2165x; 1.1908x over previous
//
#include <hip/hip_runtime.h>

// DeformConv fused pipeline, MI355X gfx950. Shapes: B=2, Ci=Co=256, H=W=96.
// R8 changes vs R7 (sample_s 152us: 288 blocks = 1.1/CU, occupancy 12.8%):
//  - sample_s: grid 288x4 (channel quarters), wave = one 8-channel slice,
//    packed uint pkw[36] register file. 1152 blocks -> real latency hiding.
//  - s_gemm: BK=32, LDS 40KB -> 2 blocks/CU (was 80KB = 1/CU); S staged by
//    waves 0-3, wave-uniform counted vmcnt(3/2).

typedef unsigned short ushort_t;
typedef unsigned int uint_t;
typedef __attribute__((ext_vector_type(8))) short bf16x8;
typedef __attribute__((ext_vector_type(4))) float f32x4;
typedef __attribute__((ext_vector_type(2), aligned(4))) float f32x2a;

#define HH 96
#define WW 96
#define HWSZ 9216
#define CI 256
#define CO 256
#define NB 2
#define NPIX 18432
#define KTOT 2304

__device__ __forceinline__ ushort_t f2bf(float f) {
  unsigned int u = __float_as_uint(f);
  u += 0x7fffu + ((u >> 16) & 1u);
  return (ushort_t)(u >> 16);
}
__device__ __forceinline__ float u2f(uint_t u) { return __uint_as_float(u); }

__device__ __forceinline__ void gload16(const void* g, void* l) {
  __builtin_amdgcn_global_load_lds(
      (const __attribute__((address_space(1))) unsigned int*)g,
      (__attribute__((address_space(3))) unsigned int*)l, 16, 0, 0);
}

// ---------------- cvt_w9: w_dcn -> bf16 [kk>>3][m][kk&7] ----------------
__global__ void cvt_w9(const float* __restrict__ w, ushort_t* __restrict__ o) {
  int i = blockIdx.x * 256 + threadIdx.x;      // grid exact CO*KTOT
  int oo = i / KTOT;
  int kk = i - oo * KTOT;
  o[(kk >> 3) * 2048 + oo * 8 + (kk & 7)] = f2bf(w[i]);
}

// ---------------- cvt_woff9: w_off -> bf16 [kk>>3][m32][kk&7], rows>=27 zero ----
__global__ void cvt_woff9(const float* __restrict__ w, ushort_t* __restrict__ o) {
  int i = blockIdx.x * 256 + threadIdx.x;      // grid exact 32*KTOT
  int m = i / KTOT;
  int kk = i - m * KTOT;
  float v = (m < 27) ? w[m * KTOT + kk] : 0.f;
  o[(kk >> 3) * 256 + m * 8 + (kk & 7)] = f2bf(v);
}

// ---------------- off_gemm: om[27][NPIX] = W27 * im2col(x) ----------------
__global__ __launch_bounds__(512, 2) void off_gemm(
    const float* __restrict__ x, const ushort_t* __restrict__ w27r,
    float* __restrict__ om) {
  __shared__ __align__(16) ushort_t A27[2][2048];
  __shared__ __align__(16) ushort_t B64[2][4096];
  __shared__ uint2 tbl[9][64];                 // {abs idx (0 if invalid), mask}

  const int tid = threadIdx.x;
  const int lane = tid & 63, wid = tid >> 6;
  const int p0 = blockIdx.x * 64;
  const int bimg = p0 / HWSZ;
  const int hw0 = p0 - bimg * HWSZ;
  const float* xb = x + (size_t)bimg * CI * HWSZ;

  for (int e = tid; e < 576; e += 512) {
    int k = e >> 6, px = e & 63;
    int hw = hw0 + px, h = hw / WW, w_ = hw - h * WW;
    int dy = k / 3 - 1, dx = k % 3 - 1;
    bool ok = (h + dy >= 0) && (h + dy < HH) && (w_ + dx >= 0) && (w_ + dx < WW);
    tbl[k][px] = make_uint2(ok ? (uint_t)(hw + dy * WW + dx) : 0u,
                            ok ? 0x3f800000u : 0u);
  }

  const int lg = lane >> 4, lm = lane & 15;
  const int wr = wid >> 2, wc = wid & 3;
  f32x4 acc = (f32x4){0.f, 0.f, 0.f, 0.f};

  int cj[8], kj[8];
#pragma unroll
  for (int j = 0; j < 8; ++j) {
    int kk = wid * 8 + j;
    cj[j] = kk / 9;
    kj[j] = kk - 9 * cj[j];
  }
  __syncthreads();

#define OG_STAGE(CH, BUF)                                                     \
  {                                                                           \
    float raw[8], mkk[8];                                                     \
    _Pragma("unroll") for (int j = 0; j < 8; ++j) {                           \
      uint2 e_ = tbl[kj[j]][lane];                                            \
      raw[j] = xb[cj[j] * HWSZ + (int)e_.x];                                  \
      mkk[j] = u2f(e_.y);                                                     \
      kj[j] += 1; cj[j] += 7;                                                 \
      if (kj[j] == 9) { kj[j] = 0; cj[j] += 1; }                              \
    }                                                                         \
    gload16(w27r + (size_t)(CH) * 2048 + (tid & 255) * 8,                     \
            &A27[BUF][(wid & 3) * 512]);                                      \
    ushort_t sv_[8] __attribute__((aligned(16)));                             \
    _Pragma("unroll") for (int j = 0; j < 8; ++j) sv_[j] = f2bf(raw[j] * mkk[j]); \
    *(uint4*)&B64[BUF][tid * 8] = *(const uint4*)sv_;                         \
  }

  OG_STAGE(0, 0)
  for (int ko = 0; ko < 36; ++ko) {
    const int cur = ko & 1, nxt = cur ^ 1;
    if (ko < 35) OG_STAGE(ko + 1, nxt)
    asm volatile("s_waitcnt vmcnt(0) lgkmcnt(0)" ::: "memory");
    __builtin_amdgcn_s_barrier();
    __builtin_amdgcn_sched_barrier(0);
#pragma unroll
    for (int s = 0; s < 2; ++s) {
      bf16x8 af = *(const bf16x8*)&A27[cur][((s * 4 + lg) * 32 + wr * 16 + lm) * 8];
      bf16x8 bfv = *(const bf16x8*)&B64[cur][((s * 4 + lg) * 64 + wc * 16 + lm) * 8];
      acc = __builtin_amdgcn_mfma_f32_16x16x32_bf16(af, bfv, acc, 0, 0, 0);
    }
    asm volatile("s_waitcnt lgkmcnt(0)" ::: "memory");
    __builtin_amdgcn_s_barrier();
    __builtin_amdgcn_sched_barrier(0);
  }
#undef OG_STAGE

  int row = wr * 16 + lg * 4;
  int col = p0 + wc * 16 + lm;
#pragma unroll
  for (int r = 0; r < 4; ++r)
    if (row + r < 27) om[(size_t)(row + r) * NPIX + col] = acc[r];
}

// ---------------- prep: om -> row-pair offsets + folded weights ----------------
__global__ void prep_kernel(const float* __restrict__ om, const float* __restrict__ b_off,
                            uint_t* __restrict__ offs, float4* __restrict__ wts) {
  int n = blockIdx.x * 128 + threadIdx.x;      // grid 144 x 128
  float omv[27];
#pragma unroll
  for (int ch = 0; ch < 27; ++ch) omv[ch] = b_off[ch] + om[(size_t)ch * NPIX + n];
  int hw = n % HWSZ;
  int h = hw / WW, w = hw - h * WW;
#pragma unroll
  for (int k = 0; k < 9; ++k) {
    float dy = omv[2 * k], dx = omv[2 * k + 1];
    float mk = 1.f / (1.f + __expf(-omv[18 + k]));
    float py = dy + (float)(h - 1 + k / 3);
    float px = dx + (float)(w - 1 + k % 3);
    float y0f = floorf(py), x0f = floorf(px);
    int y0 = (int)y0f, x0 = (int)x0f;
    float wy1 = py - y0f, wx1 = px - x0f;
    float wy0 = 1.f - wy1, wx0 = 1.f - wx1;
    float vy0 = (y0 >= 0 && y0 <= HH - 1) ? 1.f : 0.f;
    float vy1 = (y0 + 1 >= 0 && y0 + 1 <= HH - 1) ? 1.f : 0.f;
    int yc0 = min(max(y0, 0), HH - 1), yc1 = min(max(y0 + 1, 0), HH - 1);
    int xa = min(max(x0, 0), WW - 2);
    float a_, b_;
    if (x0 >= 0 && x0 <= WW - 2)      { a_ = wx0; b_ = wx1; }
    else if (x0 == -1)                { a_ = wx1; b_ = 0.f; }
    else if (x0 == WW - 1)            { a_ = 0.f; b_ = wx0; }
    else                              { a_ = 0.f; b_ = 0.f; }
    float s0 = mk * vy0 * wy0, s1 = mk * vy1 * wy1;
    offs[(size_t)k * NPIX + n] = (uint_t)(yc0 * WW + xa) | ((uint_t)(yc1 * WW + xa) << 16);
    wts[(size_t)k * NPIX + n] = make_float4(a_ * s0, b_ * s0, a_ * s1, b_ * s1);
  }
}

// ---------------- sample_s: S_g[kk>>3][n][kk&7] bf16 ----------------
// Grid 288 x 4 (channel quarters). Wave wid owns 8 channels (c-major 9-tap
// L1 reuse); 72 kk = 9 aligned groups; packed uint register file.
__global__ __launch_bounds__(512, 4) void sample_s(
    const float* __restrict__ x, const uint_t* __restrict__ offs,
    const float4* __restrict__ wts, ushort_t* __restrict__ S_g) {
  const int tid = threadIdx.x;
  const int lane = tid & 63, wid = tid >> 6;
  const int p0 = blockIdx.x * 64;
  const int part = blockIdx.y;                 // 0..3
  const int n = p0 + lane;
  const int bimg = p0 / HWSZ;
  const float* xb = x + (size_t)bimg * CI * HWSZ;

  uint_t ofr[9]; float4 wtr[9];
#pragma unroll
  for (int k = 0; k < 9; ++k) {
    ofr[k] = offs[(size_t)k * NPIX + n];
    wtr[k] = wts[(size_t)k * NPIX + n];
  }

  const int c8 = part * 64 + wid * 8;
  const size_t G0 = (size_t)9 * (part * 8 + wid);
  uint_t pkw[36];
#pragma unroll
  for (int cl = 0; cl < 8; ++cl) {
    const float* xc = xb + (size_t)(c8 + cl) * HWSZ;
#pragma unroll
    for (int k = 0; k < 9; ++k) {
      const int q = 9 * cl + k;                // static
      uint_t o2 = ofr[k];
      float4 wv = wtr[k];
      f32x2a a = *(const f32x2a*)(xc + (o2 & 0xffffu));
      f32x2a b = *(const f32x2a*)(xc + (o2 >> 16));
      uint_t bf = (uint_t)f2bf(wv.x * a.x + wv.y * a.y + wv.z * b.x + wv.w * b.y);
      if (q & 1) pkw[q >> 1] |= bf << 16; else pkw[q >> 1] = bf;
    }
    {  // group cl complete (q coverage proof: 8cl+7 <= 9cl+8, later q > 8cl+7)
      uint4 st = make_uint4(pkw[4 * cl], pkw[4 * cl + 1], pkw[4 * cl + 2], pkw[4 * cl + 3]);
      *(uint4*)&S_g[((G0 + cl) * NPIX + n) * 8] = st;
    }
  }
  {  // group 8
    uint4 st = make_uint4(pkw[32], pkw[33], pkw[34], pkw[35]);
    *(uint4*)&S_g[((G0 + 8) * NPIX + n) * 8] = st;
  }
}

// ---------------- s_gemm: out = W9 * S + b_dcn ----------------
// BM=256, BN=64, BK=32, 72 chunks, grid 288, 512 thr / 8 waves, wave 64x32.
// LDS 40KB -> 2 blocks/CU. S staged by waves 0-3 (one k-group each).
__global__ __launch_bounds__(512, 4) void s_gemm(
    const ushort_t* __restrict__ w9r, const ushort_t* __restrict__ S_g,
    const float* __restrict__ b_dcn, float* __restrict__ out) {
  __shared__ __align__(16) ushort_t A[2][8192];   // 32 KB
  __shared__ __align__(16) ushort_t S[2][2048];   // 8 KB

  const int tid = threadIdx.x;
  const int lane = tid & 63, wid = tid >> 6;
  const int p0 = blockIdx.x * 64;
  const int bimg = p0 / HWSZ;
  const int hw0 = p0 - bimg * HWSZ;
  const int lg = lane >> 4, lm = lane & 15;
  const int wr = wid >> 1, wc = wid & 1;

  f32x4 acc[4][2];
#pragma unroll
  for (int i = 0; i < 4; ++i)
#pragma unroll
    for (int j = 0; j < 2; ++j) acc[i][j] = (f32x4){0.f, 0.f, 0.f, 0.f};

#define SG_STAGE(CH, BUF)                                                     \
  {                                                                           \
    gload16(w9r + (size_t)(CH) * 8192 + tid * 8, &A[BUF][wid * 512]);         \
    gload16(w9r + (size_t)(CH) * 8192 + 4096 + tid * 8, &A[BUF][4096 + wid * 512]); \
    if (wid < 4)                                                              \
      gload16(S_g + ((size_t)((CH) * 4 + wid) * NPIX + p0 + lane) * 8,        \
              &S[BUF][wid * 512]);                                            \
  }
#define SG_MFMA(BUF)                                                          \
  {                                                                           \
    bf16x8 bfr0 = *(const bf16x8*)&S[BUF][(lg * 64 + wc * 32 + lm) * 8];      \
    bf16x8 bfr1 = *(const bf16x8*)&S[BUF][(lg * 64 + wc * 32 + 16 + lm) * 8]; \
    _Pragma("unroll") for (int mi = 0; mi < 4; ++mi) {                        \
      bf16x8 af = *(const bf16x8*)&A[BUF][(lg * 256 + wr * 64 + mi * 16 + lm) * 8]; \
      acc[mi][0] = __builtin_amdgcn_mfma_f32_16x16x32_bf16(af, bfr0, acc[mi][0], 0, 0, 0); \
      acc[mi][1] = __builtin_amdgcn_mfma_f32_16x16x32_bf16(af, bfr1, acc[mi][1], 0, 0, 0); \
    }                                                                         \
  }

  SG_STAGE(0, 0)
  for (int ko = 0; ko < 71; ++ko) {
    const int cur = ko & 1, nxt = cur ^ 1;
    SG_STAGE(ko + 1, nxt)
    if (wid < 4) { asm volatile("s_waitcnt vmcnt(3)" ::: "memory"); }
    else         { asm volatile("s_waitcnt vmcnt(2)" ::: "memory"); }
    __builtin_amdgcn_s_barrier();
    __builtin_amdgcn_sched_barrier(0);
    SG_MFMA(cur)
    asm volatile("s_waitcnt lgkmcnt(0)" ::: "memory");
    __builtin_amdgcn_s_barrier();
    __builtin_amdgcn_sched_barrier(0);
  }
  asm volatile("s_waitcnt vmcnt(0) lgkmcnt(0)" ::: "memory");
  __builtin_amdgcn_s_barrier();
  __builtin_amdgcn_sched_barrier(0);
  SG_MFMA(1)
#undef SG_STAGE
#undef SG_MFMA

  const int hwv0 = hw0 + wc * 32 + lm;
#pragma unroll
  for (int mi = 0; mi < 4; ++mi) {
    int obase = wr * 64 + mi * 16 + lg * 4;
#pragma unroll
    for (int ni = 0; ni < 2; ++ni)
#pragma unroll
      for (int r = 0; r < 4; ++r) {
        int o = obase + r;
        out[((size_t)(bimg * CO + o)) * HWSZ + hwv0 + ni * 16] = acc[mi][ni][r] + b_dcn[o];
      }
  }
}

// ---------------- fallback: R5 fused sample+GEMM (small ws) ----------------
__global__ __launch_bounds__(512, 4) void dcn_gemm(
    const float* __restrict__ x, const ushort_t* __restrict__ w9r,
    const uint_t* __restrict__ offs, const float4* __restrict__ wts,
    const float* __restrict__ b_dcn, float* __restrict__ out) {
  __shared__ __align__(16) ushort_t Alds[2][8192];
  __shared__ __align__(16) ushort_t Slds[1024];
  __shared__ uint_t off_l[9][32];
  __shared__ __align__(16) float4 wt_l[9][32];

  const int tid = threadIdx.x;
  const int p0 = blockIdx.x * 32;
  const int bimg = p0 / HWSZ;
  const int hw0 = p0 - bimg * HWSZ;
  const float* xb = x + (size_t)bimg * CI * HWSZ;

  for (int e = tid; e < 9 * 32; e += 512) {
    int k = e >> 5, p = e & 31;
    off_l[k][p] = offs[(size_t)k * NPIX + p0 + p];
    wt_l[k][p] = wts[(size_t)k * NPIX + p0 + p];
  }
  f32x4 acc[4];
#pragma unroll
  for (int i = 0; i < 4; ++i) acc[i] = (f32x4){0.f, 0.f, 0.f, 0.f};

  const int lane = tid & 63, wid = tid >> 6;
  const int wr = wid >> 1, wc = wid & 1;
  const int lg = lane >> 4, lm = lane & 15;
  const int sp = tid & 31;
  const int sk2 = tid >> 5;
  int cb, kb;
  { int kkb = sk2 * 2; cb = kkb / 9; kb = kkb - cb * 9; }

  __syncthreads();

  f32x2a r0[2], r1[2];
  {
    int c = cb, k = kb;
#pragma unroll
    for (int j = 0; j < 2; ++j) {
      uint_t o2 = off_l[k][sp];
      const float* xc = xb + c * HWSZ;
      r0[j] = *(const f32x2a*)(xc + (o2 & 0xffffu));
      r1[j] = *(const f32x2a*)(xc + (o2 >> 16));
      ++k; if (k == 9) { k = 0; ++c; }
    }
    const ushort_t* ga = w9r + tid * 8;
    gload16(ga, &Alds[0][wid * 512]);
    gload16(ga + 4096, &Alds[0][4096 + wid * 512]);
  }

  for (int ko = 0; ko < 71; ++ko) {
    const int cur = ko & 1, nxt = cur ^ 1;
    {
      float v[2];
      int k = kb;
#pragma unroll
      for (int j = 0; j < 2; ++j) {
        float4 wv = wt_l[k][sp];
        v[j] = wv.x * r0[j].x + wv.y * r0[j].y + wv.z * r1[j].x + wv.w * r1[j].y;
        ++k; if (k == 9) k = 0;
      }
      uint_t pk = (uint_t)f2bf(v[0]) | ((uint_t)f2bf(v[1]) << 16);
      *(uint_t*)&Slds[((sk2 >> 2) * 32 + sp) * 8 + (sk2 & 3) * 2] = pk;
    }
    {
      kb += 5; cb += 3;
      if (kb >= 9) { kb -= 9; ++cb; }
      int c = cb, k = kb;
#pragma unroll
      for (int j = 0; j < 2; ++j) {
        uint_t o2 = off_l[k][sp];
        const float* xc = xb + c * HWSZ;
        r0[j] = *(const f32x2a*)(xc + (o2 & 0xffffu));
        r1[j] = *(const f32x2a*)(xc + (o2 >> 16));
        ++k; if (k == 9) { k = 0; ++c; }
      }
      const ushort_t* ga = w9r + (size_t)(ko + 1) * 8192 + tid * 8;
      gload16(ga, &Alds[nxt][wid * 512]);
      gload16(ga + 4096, &Alds[nxt][4096 + wid * 512]);
    }
    asm volatile("s_waitcnt vmcnt(6) lgkmcnt(0)" ::: "memory");
    __builtin_amdgcn_s_barrier();
    __builtin_amdgcn_sched_barrier(0);
    {
      bf16x8 bfr = *(const bf16x8*)&Slds[(lg * 32 + wc * 16 + lm) * 8];
#pragma unroll
      for (int mi = 0; mi < 4; ++mi) {
        bf16x8 af = *(const bf16x8*)&Alds[cur][(lg * 256 + wr * 64 + mi * 16 + lm) * 8];
        acc[mi] = __builtin_amdgcn_mfma_f32_16x16x32_bf16(af, bfr, acc[mi], 0, 0, 0);
      }
    }
    asm volatile("s_waitcnt lgkmcnt(0)" ::: "memory");
    __builtin_amdgcn_s_barrier();
    __builtin_amdgcn_sched_barrier(0);
  }
  {
    {
      float v[2];
      int k = kb;
#pragma unroll
      for (int j = 0; j < 2; ++j) {
        float4 wv = wt_l[k][sp];
        v[j] = wv.x * r0[j].x + wv.y * r0[j].y + wv.z * r1[j].x + wv.w * r1[j].y;
        ++k; if (k == 9) k = 0;
      }
      uint_t pk = (uint_t)f2bf(v[0]) | ((uint_t)f2bf(v[1]) << 16);
      *(uint_t*)&Slds[((sk2 >> 2) * 32 + sp) * 8 + (sk2 & 3) * 2] = pk;
    }
    asm volatile("s_waitcnt vmcnt(0) lgkmcnt(0)" ::: "memory");
    __builtin_amdgcn_s_barrier();
    __builtin_amdgcn_sched_barrier(0);
    bf16x8 bfr = *(const bf16x8*)&Slds[(lg * 32 + wc * 16 + lm) * 8];
#pragma unroll
    for (int mi = 0; mi < 4; ++mi) {
      bf16x8 af = *(const bf16x8*)&Alds[1][(lg * 256 + wr * 64 + mi * 16 + lm) * 8];
      acc[mi] = __builtin_amdgcn_mfma_f32_16x16x32_bf16(af, bfr, acc[mi], 0, 0, 0);
    }
  }
  const int hwv = hw0 + wc * 16 + lm;
#pragma unroll
  for (int mi = 0; mi < 4; ++mi) {
    int obase = wr * 64 + mi * 16 + lg * 4;
#pragma unroll
    for (int r = 0; r < 4; ++r) {
      int o = obase + r;
      out[((size_t)(bimg * CO + o)) * HWSZ + hwv] = acc[mi][r] + b_dcn[o];
    }
  }
}

// ---------------- BN stats ----------------
__global__ void bn_stats(const float* __restrict__ out, const float* __restrict__ gamma,
                         const float* __restrict__ beta, float* __restrict__ ss) {
  int o = blockIdx.x;
  int tid = threadIdx.x;
  float s = 0.f, sq = 0.f;
#pragma unroll
  for (int b = 0; b < NB; ++b) {
    const float4* p = (const float4*)(out + ((size_t)(b * CO + o)) * HWSZ);
    for (int j = tid; j < HWSZ / 4; j += 256) {
      float4 v = p[j];
      s += v.x + v.y + v.z + v.w;
      sq += v.x * v.x + v.y * v.y + v.z * v.z + v.w * v.w;
    }
  }
#pragma unroll
  for (int off = 32; off > 0; off >>= 1) {
    s += __shfl_xor(s, off);
    sq += __shfl_xor(sq, off);
  }
  __shared__ float rs[4], rq[4];
  if ((tid & 63) == 0) { rs[tid >> 6] = s; rq[tid >> 6] = sq; }
  __syncthreads();
  if (tid == 0) {
    s = rs[0] + rs[1] + rs[2] + rs[3];
    sq = rq[0] + rq[1] + rq[2] + rq[3];
    float mean = s * (1.f / (float)NPIX);
    float var = sq * (1.f / (float)NPIX) - mean * mean;
    float rstd = rsqrtf(var + 1e-5f);
    float sc = rstd * gamma[o];
    ss[o] = sc;
    ss[CO + o] = beta[o] - mean * sc;
  }
}

// ---------------- BN apply + ReLU ----------------
__global__ void bn_apply(float* __restrict__ out, const float* __restrict__ ss) {
  int i = blockIdx.x * 256 + threadIdx.x;
  float4 v = ((float4*)out)[i];
  int o = (i / (HWSZ / 4)) & 255;
  float sc = ss[o], sh = ss[CO + o];
  v.x = fmaxf(v.x * sc + sh, 0.f);
  v.y = fmaxf(v.y * sc + sh, 0.f);
  v.z = fmaxf(v.z * sc + sh, 0.f);
  v.w = fmaxf(v.w * sc + sh, 0.f);
  ((float4*)out)[i] = v;
}

extern "C" void kernel_launch(void* const* d_in, const int* in_sizes, int n_in,
                              void* d_out, int out_size, void* d_ws, size_t ws_size,
                              hipStream_t stream) {
  const float* x = (const float*)d_in[0];
  const float* w_off = (const float*)d_in[1];
  const float* b_off = (const float*)d_in[2];
  const float* w_dcn = (const float*)d_in[3];
  const float* b_dcn = (const float*)d_in[4];
  const float* gamma = (const float*)d_in[5];
  const float* beta = (const float*)d_in[6];
  float* out = (float*)d_out;

  char* ws = (char*)d_ws;
  const bool big = (ws_size >= (size_t)92 * 1024 * 1024);

  size_t base = big ? 84934656 : 0;            // S_g occupies [0, 84934656) if big
  ushort_t* S_g   = (ushort_t*)(ws);
  float*    om    = (float*)(ws + base);                    // 1,990,656
  uint_t*   offs  = (uint_t*)(ws + base + 1990656);         //   663,552
  float4*   wts   = (float4*)(ws + base + 2654208);         // 2,654,208
  ushort_t* w9r   = (ushort_t*)(ws + base + 5308416);       // 1,179,648
  ushort_t* w27r  = (ushort_t*)(ws + base + 6488064);       //   147,456
  float*    ss    = (float*)(ws + base + 6635520);          //     2,048

  cvt_w9<<<(CO * KTOT) / 256, 256, 0, stream>>>(w_dcn, w9r);
  cvt_woff9<<<(32 * KTOT) / 256, 256, 0, stream>>>(w_off, w27r);
  off_gemm<<<NPIX / 64, 512, 0, stream>>>(x, w27r, om);
  prep_kernel<<<NPIX / 128, 128, 0, stream>>>(om, b_off, offs, wts);
  if (big) {
    sample_s<<<dim3(NPIX / 64, 4), 512, 0, stream>>>(x, offs, wts, S_g);
    s_gemm<<<NPIX / 64, 512, 0, stream>>>(w9r, S_g, b_dcn, out);
  } else {
    dcn_gemm<<<NPIX / 32, 512, 0, stream>>>(x, w9r, offs, wts, b_dcn, out);
  }
  bn_stats<<<CO, 256, 0, stream>>>(out, gamma, beta, ss);
  bn_apply<<<(out_size / 4) / 256, 256, 0, stream>>>(out, ss);
}